// Round 6
// baseline (186.007 us; speedup 1.0000x reference)
//
#include <hip/hip_runtime.h>
#include <math.h>

namespace {
constexpr int   NB   = 25;     // basis functions
constexpr int   TS   = 301;    // time steps
constexpr int   REC  = 28;     // floats per (dof,t) record: h[25], A, B, pad
constexpr float DT   = 0.01f;
constexpr float TAU  = 3.0f;
constexpr float AX   = 2.0f;
constexpr float AZ   = 48.0f;
constexpr float BZ   = 12.0f;  // AZ/4
constexpr int   ROWS = 131072; // BATCH * DOF
}

// ws2 layout: [dof][t][REC] = { H_k[t]*scale[dof*27+2+k] (k=0..24), A[t], B[t], 0 }
__global__ __launch_bounds__(512)
void dmp_precompute(const float* __restrict__ c, const float* __restrict__ s2,
                    const float* __restrict__ scale, float* __restrict__ ws2) {
  __shared__ float g[TS][NB];       // basis responses g_t[n]
  __shared__ float H[NB + 2][304];  // impulse tables: [0]=A, [1]=B, [2+k]=H_k
  __shared__ float cS[NB], vS[NB];
  const int tid = threadIdx.x;
  if (tid < NB) { cS[tid] = c[tid]; vS[tid] = s2[tid]; }
  __syncthreads();
  const float q = 1.0f - AX / TAU * DT;   // cx multiplier per step
  for (int i = tid; i < TS; i += 512) {
    float cx = powf(q, (float)(i + 1));   // cx updated BEFORE use in ref
    float p[NB]; float sum = 0.f;
    #pragma unroll
    for (int n = 0; n < NB; ++n) {
      float d = cx - cS[n];
      p[n] = expf(-0.5f * d * d / vS[n]);
      sum += p[n];
    }
    float m = cx / sum;
    #pragma unroll
    for (int n = 0; n < NB; ++n) g[i][n] = p[n] * m;
  }
  __syncthreads();
  // 27 independent linear-response recurrences (lanes 0..26)
  if (tid < NB + 2) {
    float y, gl;
    if (tid == 0)      { y = 1.f; gl = 0.f; }   // response to y0
    else if (tid == 1) { y = 0.f; gl = 1.f; }   // response to goal
    else               { y = 0.f; gl = 0.f; }   // response to unit w_n
    float z = 0.f;
    const int nn = (tid >= 2) ? (tid - 2) : 0;
    for (int t = 0; t < TS; ++t) {
      float fx = (tid >= 2) ? g[t][nn] : 0.f;
      float dy = z / TAU;
      float dz = (AZ * (BZ * (gl - y) - z) + fx) / TAU;
      y += dy * DT;
      z += dz * DT;
      H[tid][t] = y;
    }
  }
  __syncthreads();
  // emit scale-folded, t-major records
  constexpr int TOT = 2 * TS * REC;
  for (int idx = tid; idx < TOT; idx += 512) {
    const int dof = idx / (TS * REC);
    const int rem = idx - dof * (TS * REC);
    const int t   = rem / REC;
    const int k   = rem - t * REC;
    float v;
    if (k < NB)        v = H[2 + k][t] * scale[dof * 27 + 2 + k];
    else if (k == NB)      v = H[0][t];   // A
    else if (k == NB + 1)  v = H[1][t];   // B
    else                   v = 0.f;
    ws2[idx] = v;
  }
}

// Block = 256 threads = 4 waves; block owns 128 consecutive rows (64 batch
// pairs). Wave w: dof = w&1, t-half = w>>1; lane = one of 64 same-dof rows.
// x: 27 one-time per-lane loads (vs 54 broadcast loads per iteration before).
// Per t: 3 uniform streamed loads (ws2 record) + 25 FMAs -> 64 outputs.
// Output transposed through a per-wave-PRIVATE LDS tile (no barriers,
// [64][33] stride -> conflict-free) so global stores stay coalesced along t.
__global__ __launch_bounds__(256, 4)
void dmp_main(const float* __restrict__ x, const float* __restrict__ scale,
              const float* __restrict__ ws2, float* __restrict__ out) {
  __shared__ float tile[4][64][33];
  const int tid  = threadIdx.x;
  const int w    = tid >> 6;        // wave 0..3
  const int lane = tid & 63;
  const int dof  = w & 1;
  const int th   = w >> 1;          // t half
  const int rowbase = blockIdx.x * 128;
  const int row  = rowbase + 2 * lane + dof;

  const float* __restrict__ xr = x + (size_t)row * 27;
  const float sc_y0 = scale[dof * 27];
  const float sc_g  = scale[dof * 27 + 1];
  const float y0s = xr[0] * sc_y0;
  const float gs  = xr[1] * sc_g;
  const float d   = gs - y0s;
  float wv[NB];
  #pragma unroll
  for (int k = 0; k < NB; ++k) wv[k] = xr[2 + k] * d;   // fold (g - y0)

  const int t0    = th ? 151 : 0;
  const int tlenH = th ? 150 : 151;
  const float* __restrict__ hb = ws2 + (size_t)(dof * TS) * REC;
  float (*mytile)[33] = tile[w];

  for (int tb = 0; tb < tlenH; tb += 32) {
    const int tlen = (tlenH - tb < 32) ? (tlenH - tb) : 32;
    for (int toff = 0; toff < tlen; ++toff) {
      const int t = t0 + tb + toff;
      const float* __restrict__ hp = hb + t * REC;   // uniform address
      float a0 = 0.f, a1 = 0.f;
      #pragma unroll
      for (int k = 0; k < 24; k += 2) {
        a0 = fmaf(wv[k],     hp[k],     a0);
        a1 = fmaf(wv[k + 1], hp[k + 1], a1);
      }
      a0 = fmaf(wv[24], hp[24], a0);
      const float y = fmaf(hp[25], y0s, fmaf(hp[26], gs, a0 + a1));
      mytile[lane][toff] = y;
    }
    // transpose flush: 2 rows per pass, 32 consecutive t per half-wave
    const int r2 = lane >> 5;
    const int tf = lane & 31;
    if (tf < tlen) {
      #pragma unroll 4
      for (int p = 0; p < 32; ++p) {
        const int r = 2 * p + r2;
        const float v = mytile[r][tf];
        out[(size_t)(rowbase + 2 * r + dof) * TS + (t0 + tb + tf)] = v;
      }
    }
  }
}

extern "C" void kernel_launch(void* const* d_in, const int* in_sizes, int n_in,
                              void* d_out, int out_size, void* d_ws, size_t ws_size,
                              hipStream_t stream) {
  const float* x  = (const float*)d_in[0];
  const float* c  = (const float*)d_in[1];
  const float* s2 = (const float*)d_in[2];
  const float* sc = (const float*)d_in[3];
  float* ws2 = (float*)d_ws;   // needs 2*301*28*4 = 67,424 bytes
  float* out = (float*)d_out;

  hipLaunchKernelGGL(dmp_precompute, dim3(1), dim3(512), 0, stream,
                     c, s2, sc, ws2);
  hipLaunchKernelGGL(dmp_main, dim3(ROWS / 128), dim3(256), 0, stream,
                     x, sc, ws2, out);
}

// Round 7
// 86.034 us; speedup vs baseline: 2.1620x; 2.1620x over previous
//
#include <hip/hip_runtime.h>
#include <math.h>

namespace {
constexpr int   NB   = 25;     // basis functions
constexpr int   TS   = 301;    // time steps
constexpr int   TPAD = 304;    // padded table stride
constexpr float DT   = 0.01f;
constexpr float TAU  = 3.0f;
constexpr float AX   = 2.0f;
constexpr float AZ   = 48.0f;
constexpr float BZ   = 12.0f;  // AZ/4
constexpr int   ROWS = 131072; // BATCH * DOF

typedef float f16v __attribute__((ext_vector_type(16)));
typedef float f4v  __attribute__((ext_vector_type(4)));
typedef float f2v  __attribute__((ext_vector_type(2)));
}

// ws layout (floats): [0..TPAD) = A_t, [TPAD..2*TPAD) = B_t,
//                     [(2+n)*TPAD + t] = H_t[n]
__global__ __launch_bounds__(512)
void dmp_precompute(const float* __restrict__ c, const float* __restrict__ s2,
                    float* __restrict__ ws) {
  __shared__ float g[TS][NB];
  __shared__ float cS[NB], vS[NB];
  const int tid = threadIdx.x;
  if (tid < NB) { cS[tid] = c[tid]; vS[tid] = s2[tid]; }
  __syncthreads();
  const float q = 1.0f - AX / TAU * DT;   // cx multiplier per step
  for (int i = tid; i < TS; i += 512) {
    float cx = powf(q, (float)(i + 1));   // cx updated BEFORE use in ref
    float p[NB]; float sum = 0.f;
    #pragma unroll
    for (int n = 0; n < NB; ++n) {
      float d = cx - cS[n];
      p[n] = expf(-0.5f * d * d / vS[n]);
      sum += p[n];
    }
    float m = cx / sum;
    #pragma unroll
    for (int n = 0; n < NB; ++n) g[i][n] = p[n] * m;
  }
  __syncthreads();
  // 27 independent linear-response recurrences (lanes 0..26)
  if (tid < NB + 2) {
    float y, gl;
    if (tid == 0)      { y = 1.f; gl = 0.f; }   // response to y0
    else if (tid == 1) { y = 0.f; gl = 1.f; }   // response to goal
    else               { y = 0.f; gl = 0.f; }   // response to unit w_n
    float z = 0.f;
    const int nn = (tid >= 2) ? (tid - 2) : 0;
    float* dst = ws + tid * TPAD;
    for (int t = 0; t < TS; ++t) {
      float fx = (tid >= 2) ? g[t][nn] : 0.f;
      float dy = z / TAU;
      float dz = (AZ * (BZ * (gl - y) - z) + fx) / TAU;
      y += dy * DT;
      z += dz * DT;
      dst[t] = y;
    }
  }
}

// Block = 320 threads = 5 waves (one per 64-t chunk), 64 rows per block.
// Per-lane t-tables (a, b, h0/h1[25]) pinned in VGPRs via empty asm.
// Row data (2 rows = 54 floats/iter) read via explicit inline-asm s_load
// into SGPRs (R2-R6 failure: compiler never selected the scalar path; the
// 54-float broadcast went down VMEM/LDS with per-element addressing).
// FMAs consume SGPR x VGPR (one SGPR src per VALU instr - legal).
// Stores: 64 consecutive t per instruction, fully coalesced.
__global__ __launch_bounds__(320, 4)
void dmp_main(const float* __restrict__ x, const float* __restrict__ scale,
              const float* __restrict__ ws, float* __restrict__ out) {
  const int tid  = threadIdx.x;
  const int lane = tid & 63;
  const int tc   = tid >> 6;          // 0..4
  const int rg   = blockIdx.x;        // row group (64 rows)
  const int t    = tc * 64 + lane;
  const int tl   = (t < TS) ? t : (TS - 1);
  const bool tv  = (t < TS);

  float a = ws[tl];
  float b = ws[TPAD + tl];
  float h0[NB], h1[NB];
  #pragma unroll
  for (int k = 0; k < NB; ++k) {
    const float h = ws[(2 + k) * TPAD + tl];
    h0[k] = h * scale[2 + k];          // dof 0
    h1[k] = h * scale[29 + k];         // dof 1
  }
  float s00 = scale[0],  s01 = scale[1];
  float s10 = scale[27], s11 = scale[28];

  // Pin loop-invariant per-lane values into VGPRs (cannot be rematerialized).
  asm volatile("" : "+v"(a), "+v"(b), "+v"(s00), "+v"(s01), "+v"(s10), "+v"(s11));
  #pragma unroll
  for (int k = 0; k < NB; ++k) {
    asm volatile("" : "+v"(h0[k]), "+v"(h1[k]));
  }

  const int row0 = rg << 6;
  const float* __restrict__ xb = x + (size_t)row0 * 27;

  #pragma unroll 1
  for (int rr = 0; rr < 64; rr += 2) {
    const float* p = xb + rr * 27;     // uniform address (blockIdx + counter)

    // 54 floats = 216 B exactly: x16,x16,x16,x4,x2 on the scalar pipe.
    f16v A0, A1, A2; f4v A3; f2v A4;
    asm volatile(
      "s_load_dwordx16 %0, %5, 0x0\n\t"
      "s_load_dwordx16 %1, %5, 0x40\n\t"
      "s_load_dwordx16 %2, %5, 0x80\n\t"
      "s_load_dwordx4  %3, %5, 0xc0\n\t"
      "s_load_dwordx2  %4, %5, 0xd0\n\t"
      "s_waitcnt lgkmcnt(0)"
      : "=s"(A0), "=s"(A1), "=s"(A2), "=s"(A3), "=s"(A4)
      : "s"(p));

    float xx[54];
    #pragma unroll
    for (int i = 0; i < 16; ++i) xx[i] = A0[i];
    #pragma unroll
    for (int i = 0; i < 16; ++i) xx[16 + i] = A1[i];
    #pragma unroll
    for (int i = 0; i < 16; ++i) xx[32 + i] = A2[i];
    #pragma unroll
    for (int i = 0; i < 4; ++i)  xx[48 + i] = A3[i];
    xx[52] = A4[0]; xx[53] = A4[1];

    float accA0 = 0.f, accA1 = 0.f, accB0 = 0.f, accB1 = 0.f;
    #pragma unroll
    for (int k = 0; k < 24; k += 2) {
      accA0 = fmaf(xx[2 + k],  h0[k],     accA0);
      accA1 = fmaf(xx[3 + k],  h0[k + 1], accA1);
      accB0 = fmaf(xx[29 + k], h1[k],     accB0);
      accB1 = fmaf(xx[30 + k], h1[k + 1], accB1);
    }
    accA0 = fmaf(xx[26], h0[24], accA0);
    accB0 = fmaf(xx[53], h1[24], accB0);
    const float accA = accA0 + accA1;
    const float accB = accB0 + accB1;

    const float y0A = xx[0]  * s00, gA = xx[1]  * s01;
    const float y0B = xx[27] * s10, gB = xx[28] * s11;
    const float yA = fmaf(a, y0A, b * gA) + (gA - y0A) * accA;
    const float yB = fmaf(a, y0B, b * gB) + (gB - y0B) * accB;
    if (tv) {
      out[(size_t)(row0 + rr) * TS + t]     = yA;
      out[(size_t)(row0 + rr + 1) * TS + t] = yB;
    }
  }
}

extern "C" void kernel_launch(void* const* d_in, const int* in_sizes, int n_in,
                              void* d_out, int out_size, void* d_ws, size_t ws_size,
                              hipStream_t stream) {
  const float* x  = (const float*)d_in[0];
  const float* c  = (const float*)d_in[1];
  const float* s2 = (const float*)d_in[2];
  const float* sc = (const float*)d_in[3];
  float* ws  = (float*)d_ws;   // needs 27*304*4 = 32,832 bytes
  float* out = (float*)d_out;

  hipLaunchKernelGGL(dmp_precompute, dim3(1), dim3(512), 0, stream, c, s2, ws);
  hipLaunchKernelGGL(dmp_main, dim3(ROWS / 64), dim3(320), 0, stream,
                     x, sc, ws, out);
}

// Round 9
// 79.214 us; speedup vs baseline: 2.3482x; 1.0861x over previous
//
#include <hip/hip_runtime.h>
#include <math.h>

namespace {
constexpr int   NB   = 25;     // basis functions
constexpr int   TS   = 301;    // time steps
constexpr int   TPAD = 304;    // padded table stride
constexpr float DT   = 0.01f;
constexpr float TAU  = 3.0f;
constexpr float AX   = 2.0f;
constexpr float AZ   = 48.0f;
constexpr float BZ   = 12.0f;  // AZ/4
constexpr int   ROWS = 131072; // BATCH * DOF

typedef float f16v __attribute__((ext_vector_type(16)));
typedef float f8v  __attribute__((ext_vector_type(8)));
typedef float f2v  __attribute__((ext_vector_type(2)));

__device__ inline const float* uniform_ptr(const float* p) {
  // rbase is wave-constant; make that visible to the compiler so the
  // pointer lands in SGPRs (R8 failure: divergence analysis put the
  // "s"-constrained asm operand in VGPRs -> illegal s_load operand).
  uint64_t u  = (uint64_t)p;
  uint32_t lo = __builtin_amdgcn_readfirstlane((uint32_t)u);
  uint32_t hi = __builtin_amdgcn_readfirstlane((uint32_t)(u >> 32));
  return (const float*)(((uint64_t)hi << 32) | lo);
}
}

// ws layout (floats): [0..TPAD) = A_t, [TPAD..2*TPAD) = B_t,
//                     [(2+n)*TPAD + t] = H_t[n]
__global__ __launch_bounds__(512)
void dmp_precompute(const float* __restrict__ c, const float* __restrict__ s2,
                    float* __restrict__ ws) {
  __shared__ float g[TS][NB];
  __shared__ float cS[NB], vS[NB];
  const int tid = threadIdx.x;
  if (tid < NB) { cS[tid] = c[tid]; vS[tid] = s2[tid]; }
  __syncthreads();
  const float q = 1.0f - AX / TAU * DT;   // cx multiplier per step
  for (int i = tid; i < TS; i += 512) {
    float cx = powf(q, (float)(i + 1));   // cx updated BEFORE use in ref
    float p[NB]; float sum = 0.f;
    #pragma unroll
    for (int n = 0; n < NB; ++n) {
      float d = cx - cS[n];
      p[n] = expf(-0.5f * d * d / vS[n]);
      sum += p[n];
    }
    float m = cx / sum;
    #pragma unroll
    for (int n = 0; n < NB; ++n) g[i][n] = p[n] * m;
  }
  __syncthreads();
  // 27 independent linear-response recurrences (lanes 0..26)
  if (tid < NB + 2) {
    float y, gl;
    if (tid == 0)      { y = 1.f; gl = 0.f; }   // response to y0
    else if (tid == 1) { y = 0.f; gl = 1.f; }   // response to goal
    else               { y = 0.f; gl = 0.f; }   // response to unit w_n
    float z = 0.f;
    const int nn = (tid >= 2) ? (tid - 2) : 0;
    float* dst = ws + tid * TPAD;
    for (int t = 0; t < TS; ++t) {
      float fx = (tid >= 2) ? g[t][nn] : 0.f;
      float dy = z / TAU;
      float dz = (AZ * (BZ * (gl - y) - z) + fx) / TAU;
      y += dy * DT;
      z += dz * DT;
      dst[t] = y;
    }
  }
}

// Wave = 64 same-dof rows x ALL 301 t (5 t per lane: t = lane + 64c).
// h-tables for the wave's dof (a[5],b[5],h[5][25] = 135 VGPR) resident.
// Row data: 27 floats via double-buffered inline-asm s_load (SMEM),
// prefetch pipelined one row deep; each x byte read once chip-wide.
// Stores: 5 x 256B coalesced per row (masked tail chunk). Zero LDS.
__global__ __launch_bounds__(256, 2)
void dmp_main(const float* __restrict__ x, const float* __restrict__ scale,
              const float* __restrict__ ws, float* __restrict__ out) {
  const int tid  = threadIdx.x;
  const int w    = tid >> 6;
  const int lane = tid & 63;
  const int dof  = w & 1;
  const int rbase = blockIdx.x * 256 + (w >> 1) * 128 + dof; // first row (this dof)

  // per-lane t-tables for 5 chunks
  float a0, a1, a2, a3, a4, b0, b1, b2, b3, b4;
  float h0[NB], h1[NB], h2[NB], h3[NB], h4[NB];
  {
    const int t0 = lane, t1 = lane + 64, t2 = lane + 128, t3 = lane + 192;
    const int t4 = (lane + 256 < TS) ? (lane + 256) : (TS - 1);
    a0 = ws[t0]; a1 = ws[t1]; a2 = ws[t2]; a3 = ws[t3]; a4 = ws[t4];
    b0 = ws[TPAD + t0]; b1 = ws[TPAD + t1]; b2 = ws[TPAD + t2];
    b3 = ws[TPAD + t3]; b4 = ws[TPAD + t4];
    #pragma unroll
    for (int k = 0; k < NB; ++k) {
      const float sk = scale[dof * 27 + 2 + k];
      const float* hp = ws + (2 + k) * TPAD;
      h0[k] = hp[t0] * sk; h1[k] = hp[t1] * sk; h2[k] = hp[t2] * sk;
      h3[k] = hp[t3] * sk; h4[k] = hp[t4] * sk;
    }
  }
  float vs0 = scale[dof * 27], vs1 = scale[dof * 27 + 1];
  // pin tables resident (R4 lesson: allocator sinks loop-invariant loads)
  asm volatile("" : "+v"(a0), "+v"(a1), "+v"(a2), "+v"(a3), "+v"(a4));
  asm volatile("" : "+v"(b0), "+v"(b1), "+v"(b2), "+v"(b3), "+v"(b4));
  asm volatile("" : "+v"(vs0), "+v"(vs1));
  #pragma unroll
  for (int k = 0; k < NB; ++k) {
    asm volatile("" : "+v"(h0[k]), "+v"(h1[k]), "+v"(h2[k]), "+v"(h3[k]), "+v"(h4[k]));
  }

  const bool tail = (lane < TS - 256);   // 45 valid lanes in chunk 4

#define ISSUE(A0, A1, A2, A3, P, DEP)                                   \
  asm volatile("s_load_dwordx16 %0, %4, 0x0\n\t"                        \
               "s_load_dwordx8  %1, %4, 0x40\n\t"                       \
               "s_load_dwordx2  %2, %4, 0x60\n\t"                       \
               "s_load_dword    %3, %4, 0x68"                           \
               : "=s"(A0), "=s"(A1), "=s"(A2), "=s"(A3)                 \
               : "s"(P), "s"(DEP))

#define WAITB(A0, A1, A2, A3)                                           \
  asm volatile("s_waitcnt lgkmcnt(0)"                                   \
               : "+s"(A0), "+s"(A1), "+s"(A2), "+s"(A3))

#define BODY(A0, A1, A2, A3, OB)                                        \
  do {                                                                  \
    const float y0s = A0[0] * vs0;                                      \
    const float gs  = A0[1] * vs1;                                      \
    const float dd  = gs - y0s;                                         \
    float dA0 = 0.f, dA1 = 0.f, dB0 = 0.f, dB1 = 0.f, dC0 = 0.f,        \
          dC1 = 0.f, dD0 = 0.f, dD1 = 0.f, dE0 = 0.f, dE1 = 0.f;        \
    _Pragma("unroll")                                                   \
    for (int k = 0; k < 24; k += 2) {                                   \
      const float xk  = (k < 14) ? A0[k + 2] : (k < 22) ? A1[k - 14]    \
                                             : A2[k - 22];              \
      const float xk1 = (k + 1 < 14) ? A0[k + 3]                        \
                        : (k + 1 < 22) ? A1[k - 13]                     \
                        : (k + 1 < 24) ? A2[k - 21] : A3;               \
      dA0 = fmaf(xk, h0[k], dA0); dA1 = fmaf(xk1, h0[k + 1], dA1);      \
      dB0 = fmaf(xk, h1[k], dB0); dB1 = fmaf(xk1, h1[k + 1], dB1);      \
      dC0 = fmaf(xk, h2[k], dC0); dC1 = fmaf(xk1, h2[k + 1], dC1);      \
      dD0 = fmaf(xk, h3[k], dD0); dD1 = fmaf(xk1, h3[k + 1], dD1);      \
      dE0 = fmaf(xk, h4[k], dE0); dE1 = fmaf(xk1, h4[k + 1], dE1);      \
    }                                                                   \
    const float x24 = A3;                                               \
    dA0 = fmaf(x24, h0[24], dA0); dB0 = fmaf(x24, h1[24], dB0);         \
    dC0 = fmaf(x24, h2[24], dC0); dD0 = fmaf(x24, h3[24], dD0);         \
    dE0 = fmaf(x24, h4[24], dE0);                                       \
    float* orow = out + (OB);                                           \
    orow[lane]       = fmaf(a0, y0s, fmaf(b0, gs, dd * (dA0 + dA1)));   \
    orow[lane + 64]  = fmaf(a1, y0s, fmaf(b1, gs, dd * (dB0 + dB1)));   \
    orow[lane + 128] = fmaf(a2, y0s, fmaf(b2, gs, dd * (dC0 + dC1)));   \
    orow[lane + 192] = fmaf(a3, y0s, fmaf(b3, gs, dd * (dD0 + dD1)));   \
    if (tail) orow[lane + 256] =                                        \
        fmaf(a4, y0s, fmaf(b4, gs, dd * (dE0 + dE1)));                  \
  } while (0)

  f16v Pa, Qa; f8v Pb, Qb; f2v Pc, Qc; float Pd, Qd;
  const float* pc = uniform_ptr(x + (size_t)rbase * 27); // wave's row i base
  size_t ob = (size_t)rbase * TS;

  ISSUE(Pa, Pb, Pc, Pd, pc, pc);
  #pragma unroll 1
  for (int i = 0; i < 64; i += 2) {
    WAITB(Pa, Pb, Pc, Pd);
    const float* pn1 = pc + 54;                        // row i+1 (i<=62 -> valid)
    ISSUE(Qa, Qb, Qc, Qd, pn1, Pa[0]);
    BODY(Pa, Pb, Pc, Pd, ob);

    WAITB(Qa, Qb, Qc, Qd);
    const float* pn2 = (i + 2 < 64) ? (pc + 108) : pn1; // clamp final prefetch
    ISSUE(Pa, Pb, Pc, Pd, pn2, Qa[0]);
    BODY(Qa, Qb, Qc, Qd, ob + 2 * TS);

    pc += 108;
    ob += (size_t)4 * TS;
  }
#undef ISSUE
#undef WAITB
#undef BODY
}

extern "C" void kernel_launch(void* const* d_in, const int* in_sizes, int n_in,
                              void* d_out, int out_size, void* d_ws, size_t ws_size,
                              hipStream_t stream) {
  const float* x  = (const float*)d_in[0];
  const float* c  = (const float*)d_in[1];
  const float* s2 = (const float*)d_in[2];
  const float* sc = (const float*)d_in[3];
  float* ws  = (float*)d_ws;   // needs 27*304*4 = 32,832 bytes
  float* out = (float*)d_out;

  hipLaunchKernelGGL(dmp_precompute, dim3(1), dim3(512), 0, stream, c, s2, ws);
  hipLaunchKernelGGL(dmp_main, dim3(ROWS / 256), dim3(256), 0, stream,
                     x, sc, ws, out);
}